// Round 1
// baseline (45845.380 us; speedup 1.0000x reference)
//
#include <hip/hip_runtime.h>

#define TDEC 400
#define NTH 512
#define NWG 256
#define NEG_INF -1e9f

// ---------------- ws layout (float offsets) ----------------
#define OFF_BAR    0
#define OFF_ATTH   256
#define OFF_H1     (OFF_ATTH + 32768)
#define OFF_H2     (OFF_H1 + 32768)
#define OFF_CUR    (OFF_H2 + 32768)
#define MEMSET_FLOATS (OFF_CUR + 16384)
#define OFF_DECIN  MEMSET_FLOATS
#define OFF_D1     (OFF_DECIN + 16384)
#define OFF_QWS    (OFF_D1 + 16384)
#define OFF_EWS    (OFF_QWS + 16384)
#define OFF_ATTM   (OFF_EWS + 32768)
#define OFF_ATTS   (OFF_ATTM + 256)
#define OFF_ATTP   (OFF_ATTS + 256)
#define OFF_PRE    (OFF_ATTP + 65536)
#define OFF_PM     (OFF_PRE + 3276800)
#define OFF_D2     (OFF_PM + 8388608)
#define OFF_WIT_A  (OFF_D2 + 6553600)
#define OFF_WHT_A  (OFF_WIT_A + 294912)
#define OFF_WIT_1  (OFF_WHT_A + 196608)
#define OFF_WHT_1  (OFF_WIT_1 + 196608)
#define OFF_WIT_2  (OFF_WHT_1 + 196608)
#define OFF_WHT_2  (OFF_WIT_2 + 196608)
#define OFF_PROJT  (OFF_WHT_2 + 196608)
#define OFF_QWT    (OFF_PROJT + 131072)
#define WS_FLOATS  (OFF_QWT + 65536)

#define AOFF 4096000     // alignments offset in d_out (floats)
#define GOFF 17203200    // gates offset in d_out (floats)

// barrier slots (int indices inside OFF_BAR region)
#define MSTI 128
#define GENI 136
#define FAILI 140

__device__ __forceinline__ float fsig(float x){ return 1.0f/(1.0f+__expf(-x)); }
__device__ __forceinline__ float ftanh(float x){ float e = __expf(2.0f*x); return 1.0f - 2.0f/(e+1.0f); }
__device__ __forceinline__ float dot4(float4 a, float4 b){ return a.x*b.x + a.y*b.y + a.z*b.z + a.w*b.w; }

// two-level grid barrier: 8 spread counters (32 WGs each) -> master -> generation
__device__ __forceinline__ void gbar(int* bar, int wg){
  __syncthreads();
  if (threadIdx.x == 0){
    if (__hip_atomic_load(&bar[FAILI], __ATOMIC_RELAXED, __HIP_MEMORY_SCOPE_AGENT) == 0){
      __builtin_amdgcn_fence(__ATOMIC_RELEASE, "agent");
      int g = __hip_atomic_load(&bar[GENI], __ATOMIC_RELAXED, __HIP_MEMORY_SCOPE_AGENT);
      int a = __hip_atomic_fetch_add(&bar[(wg & 7) * 16], 1, __ATOMIC_RELAXED, __HIP_MEMORY_SCOPE_AGENT);
      if (a == 31){
        __hip_atomic_store(&bar[(wg & 7) * 16], 0, __ATOMIC_RELAXED, __HIP_MEMORY_SCOPE_AGENT);
        int m = __hip_atomic_fetch_add(&bar[MSTI], 1, __ATOMIC_ACQ_REL, __HIP_MEMORY_SCOPE_AGENT);
        if (m == 7){
          __hip_atomic_store(&bar[MSTI], 0, __ATOMIC_RELAXED, __HIP_MEMORY_SCOPE_AGENT);
          __hip_atomic_store(&bar[GENI], g + 1, __ATOMIC_RELEASE, __HIP_MEMORY_SCOPE_AGENT);
        }
      }
      int sp = 0;
      while (__hip_atomic_load(&bar[GENI], __ATOMIC_RELAXED, __HIP_MEMORY_SCOPE_AGENT) == g){
        __builtin_amdgcn_s_sleep(2);
        if (++sp > (1 << 22)){
          __hip_atomic_store(&bar[FAILI], 1, __ATOMIC_RELAXED, __HIP_MEMORY_SCOPE_AGENT);
          break;
        }
      }
      __builtin_amdgcn_fence(__ATOMIC_ACQUIRE, "agent");
    }
  }
  __syncthreads();
}

// ---------------- generic 32x32 tiled transpose: in[K][C] -> out[C][K] ----------------
__global__ __launch_bounds__(256, 1) void transpose_k(const float* __restrict__ in,
                                                      float* __restrict__ outp, int K, int C){
  __shared__ float tl[32][33];
  int c0 = blockIdx.x * 32, k0 = blockIdx.y * 32;
  int tx = threadIdx.x & 31, ty = threadIdx.x >> 5;
  for (int i = ty; i < 32; i += 8){
    int k = k0 + i, c = c0 + tx;
    if (k < K && c < C) tl[i][tx] = in[k * C + c];
  }
  __syncthreads();
  for (int i = ty; i < 32; i += 8){
    int c = c0 + i, k = k0 + tx;
    if (c < C && k < K) outp[c * K + k] = tl[tx][i];
  }
}

// ---------------- prenet for all 400 steps (teacher forcing shift), b-major output ----------------
// grid (400, 2): t, b-half of 32
__global__ __launch_bounds__(NTH, 1) void prenet_k(float* __restrict__ ws,
    const float* __restrict__ inp, const float* __restrict__ W1, const float* __restrict__ B1,
    const float* __restrict__ W2, const float* __restrict__ B2){
  __shared__ float xT[160 * 33];
  __shared__ float hT[256 * 33];
  int t = blockIdx.x, half = blockIdx.y, tid = threadIdx.x;
  int bbase = half * 32;
  for (int r = tid; r < 32 * 160; r += NTH){
    int b2 = r / 160; int k = r - b2 * 160;
    xT[k * 33 + b2] = (t == 0) ? 0.f : inp[((bbase + b2) * TDEC + (t - 1)) * 160 + k];
  }
  __syncthreads();
  int bl = tid & 31, slot = tid >> 5;   // slot < 16
  float acc1[16];
  #pragma unroll
  for (int i = 0; i < 16; ++i) acc1[i] = 0.f;
  for (int k = 0; k < 160; ++k){
    float xv = xT[k * 33 + bl];
    const float* wr = W1 + k * 256 + slot * 16;
    #pragma unroll
    for (int i = 0; i < 16; ++i) acc1[i] += xv * wr[i];
  }
  #pragma unroll
  for (int i = 0; i < 16; ++i){
    int c = slot * 16 + i;
    hT[c * 33 + bl] = fmaxf(acc1[i] + B1[c], 0.f);
  }
  __syncthreads();
  float acc2[8];
  #pragma unroll
  for (int i = 0; i < 8; ++i) acc2[i] = 0.f;
  for (int k = 0; k < 256; ++k){
    float hv = hT[k * 33 + bl];
    const float* wr = W2 + k * 128 + slot * 8;
    #pragma unroll
    for (int i = 0; i < 8; ++i) acc2[i] += hv * wr[i];
  }
  float* dst = ws + OFF_PRE + t * 8192 + (bbase + bl) * 128 + slot * 8;
  #pragma unroll
  for (int i = 0; i < 8; ++i) dst[i] = fmaxf(acc2[i] + B2[slot * 8 + i], 0.f);
}

// ---------------- processed_memory = enc @ mem_W  (pm[b][t][d]) ----------------
// grid 512: (b 64) x (t-tile 8)
__global__ __launch_bounds__(NTH, 1) void pm_k(float* __restrict__ ws,
    const float* __restrict__ enc, const float* __restrict__ memW){
  int wg = blockIdx.x, tid = threadIdx.x;
  int b = wg & 63, th = wg >> 6;
  int slot = tid & 7, tt = tid >> 3;
  int trow = th * 64 + tt;
  const float* er = enc + (b * 512 + trow) * 256;
  float4 acc[8];
  #pragma unroll
  for (int i = 0; i < 8; ++i) acc[i] = make_float4(0.f, 0.f, 0.f, 0.f);
  for (int k = 0; k < 256; ++k){
    float ev = er[k];
    const float4* wr = (const float4*)(memW + k * 256 + slot * 32);
    #pragma unroll
    for (int i = 0; i < 8; ++i){
      float4 w4 = wr[i];
      acc[i].x += ev * w4.x; acc[i].y += ev * w4.y;
      acc[i].z += ev * w4.z; acc[i].w += ev * w4.w;
    }
  }
  float4* dst = (float4*)(ws + OFF_PM + (b * 512 + trow) * 256 + slot * 32);
  #pragma unroll
  for (int i = 0; i < 8; ++i) dst[i] = acc[i];
}

// ---------------- persistent recurrent decoder ----------------
__global__ __launch_bounds__(NTH, 1) void decoder_k(
    float* __restrict__ ws, float* __restrict__ out,
    const float* __restrict__ enc, const int* __restrict__ memlen,
    const float* __restrict__ vW,
    const float* __restrict__ attBi, const float* __restrict__ attBh,
    const float* __restrict__ projB,
    const float* __restrict__ d1Bi, const float* __restrict__ d1Bh,
    const float* __restrict__ d2Bi, const float* __restrict__ d2Bh)
{
  const int wg = blockIdx.x, tid = threadIdx.x;
  int* bar = (int*)ws;
  float* attH = ws + OFF_ATTH;       // [2][64][256] b-major
  float* h1a  = ws + OFF_H1;
  float* h2a  = ws + OFF_H2;
  float* cur  = ws + OFF_CUR;        // [64][256]
  float* decin= ws + OFF_DECIN;
  float* d1v  = ws + OFF_D1;
  float* qws  = ws + OFF_QWS;        // [64][256]
  float* ews  = ws + OFF_EWS;        // [64][512]
  float* attM = ws + OFF_ATTM;
  float* attS = ws + OFF_ATTS;
  float* attP = ws + OFF_ATTP;       // [64][4][256]
  const float* preB = ws + OFF_PRE;  // [400][64][128]
  const float* pm   = ws + OFF_PM;   // [64][512][256]
  float* d2a  = ws + OFF_D2;         // [400][256][64]  (j-major, b inner)
  const float* wiA = ws + OFF_WIT_A; // [768][384]
  const float* whA = ws + OFF_WHT_A; // [768][256]
  const float* wi1 = ws + OFF_WIT_1;
  const float* wh1 = ws + OFF_WHT_1;
  const float* wi2 = ws + OFF_WIT_2;
  const float* wh2 = ws + OFF_WHT_2;
  const float* pjT = ws + OFF_PROJT; // [256][512]
  const float* qWT = ws + OFF_QWT;   // [256][256]

  __shared__ float ewGi[12 * 16], ewGh[12 * 16];
  __shared__ float qL[256], vL[256];
  __shared__ float psc[128 * 4], scL[128], eL[128];
  __shared__ float redL[2];
  __shared__ float pc[2 * 256], pp[64 * 8];
  __shared__ float caL[16 * 260], combL[16 * 4];

  if (tid < 256) vL[tid] = vW[tid];

  const int bg = wg & 3, sl = wg >> 2;     // roles for P0,P1,P3,P4,P5
  const int b0 = bg << 4;
  const int b2 = wg & 63, ch2 = wg >> 6;   // role for P2 (scoring)
  const int len2 = memlen[b2];

  const int bq = tid & 15, x = tid >> 4;
  const int cs = (x >= 12) ? (x - 12) : x;     // [0,12)
  const int gg = cs % 3, jh = cs / 3;
  const int col = gg * 256 + sl * 4 + jh;
  const int bb_ = b0 + bq;

  for (int t = 0; t < TDEC; ++t){
    const int p = t & 1, pn = p ^ 1;
    const float* aHp = attH + p * 16384;
    float* aHn = attH + pn * 16384;

    // ===== P0: attention GRU  (att_h' = GRU(cat(pre, cur_att), att_h)) =====
    {
      float acc = 0.f;
      if (x < 12){          // gi over cell_in = [pre(128), cur_att(256)]
        const float4* w4 = (const float4*)(wiA + col * 384);
        const float4* xp = (const float4*)(preB + t * 8192 + bb_ * 128);
        #pragma unroll
        for (int k = 0; k < 32; ++k) acc += dot4(xp[k], w4[k]);
        const float4* cp = (const float4*)(cur + bb_ * 256);
        #pragma unroll
        for (int k = 0; k < 64; ++k) acc += dot4(cp[k], w4[32 + k]);
        ewGi[cs * 16 + bq] = acc + attBi[col];
      } else if (x < 24){   // gh over att_h
        const float4* w4 = (const float4*)(whA + col * 256);
        const float4* hp = (const float4*)(aHp + bb_ * 256);
        #pragma unroll
        for (int k = 0; k < 64; ++k) acc += dot4(hp[k], w4[k]);
        ewGh[cs * 16 + bq] = acc + attBh[col];
      }
      __syncthreads();
      if (tid < 64){
        int bt = tid & 15, jj = tid >> 4;
        int bbb = b0 + bt, j = sl * 4 + jj;
        float ir = ewGi[(jj*3+0)*16+bt] + ewGh[(jj*3+0)*16+bt];
        float iz = ewGi[(jj*3+1)*16+bt] + ewGh[(jj*3+1)*16+bt];
        float inn = ewGi[(jj*3+2)*16+bt];
        float hn  = ewGh[(jj*3+2)*16+bt];
        float r = fsig(ir), z = fsig(iz);
        float n = ftanh(inn + r * hn);
        float h = aHp[bbb * 256 + j];
        aHn[bbb * 256 + j] = (1.f - z) * n + z * h;
      }
    }
    gbar(bar, wg);

    // ===== P1: q = att_h' @ q_W =====
    {
      int dotid = tid >> 3, sg = tid & 7;
      int qb = b0 + (dotid & 15), dd = dotid >> 4;
      int d = sl * 4 + dd;
      const float4* hp = (const float4*)(aHn + qb * 256 + sg * 32);
      const float4* w4 = (const float4*)(qWT + d * 256 + sg * 32);
      float acc = 0.f;
      #pragma unroll
      for (int k = 0; k < 8; ++k) acc += dot4(hp[k], w4[k]);
      pp[dotid * 8 + sg] = acc;
      __syncthreads();
      if (tid < 64){
        float s = 0.f;
        #pragma unroll
        for (int i = 0; i < 8; ++i) s += pp[tid * 8 + i];
        qws[(b0 + (tid & 15)) * 256 + sl * 4 + (tid >> 4)] = s;
      }
    }
    gbar(bar, wg);

    // ===== P2: scoring + softmax partials + context partials  (wg = b x chunk128) =====
    {
      if (tid < 256) qL[tid] = qws[b2 * 256 + tid];
      __syncthreads();
      int tt = tid >> 2, part = tid & 3;
      int te = ch2 * 128 + tt;
      float a4 = 0.f;
      if (te < len2){
        const float4* pmp = (const float4*)(pm + (b2 * 512 + te) * 256 + part * 64);
        const float4* q4 = (const float4*)(qL + part * 64);
        const float4* v4 = (const float4*)(vL + part * 64);
        #pragma unroll
        for (int i = 0; i < 16; ++i){
          float4 pv = pmp[i], qv = q4[i], vv = v4[i];
          a4 += ftanh(pv.x + qv.x) * vv.x + ftanh(pv.y + qv.y) * vv.y
              + ftanh(pv.z + qv.z) * vv.z + ftanh(pv.w + qv.w) * vv.w;
        }
      }
      psc[tt * 4 + part] = a4;
      __syncthreads();
      if (tid < 128){
        float s = (ch2 * 128 + tid < len2)
                ? (psc[tid*4+0] + psc[tid*4+1] + psc[tid*4+2] + psc[tid*4+3])
                : NEG_INF;
        scL[tid] = s;
      }
      __syncthreads();
      if (tid < 64){
        float m = fmaxf(scL[tid], scL[tid + 64]);
        #pragma unroll
        for (int o = 32; o > 0; o >>= 1) m = fmaxf(m, __shfl_down(m, o));
        if (tid == 0) redL[0] = m;
      }
      __syncthreads();
      float mc = redL[0];
      if (tid < 128){
        float e = __expf(scL[tid] - mc);
        eL[tid] = e;
        ews[b2 * 512 + ch2 * 128 + tid] = e;
      }
      __syncthreads();
      if (tid < 64){
        float s = eL[tid] + eL[tid + 64];
        #pragma unroll
        for (int o = 32; o > 0; o >>= 1) s += __shfl_down(s, o);
        if (tid == 0){ attM[b2 * 4 + ch2] = mc; attS[b2 * 4 + ch2] = s; }
      }
      {
        int d = tid & 255, hf = tid >> 8;
        const float* ep = enc + (b2 * 512 + ch2 * 128 + hf * 64) * 256 + d;
        float acc = 0.f;
        #pragma unroll 8
        for (int i = 0; i < 64; ++i) acc += eL[hf * 64 + i] * ep[i * 256];
        pc[hf * 256 + d] = acc;
      }
      __syncthreads();
      if (tid < 256) attP[(b2 * 4 + ch2) * 256 + tid] = pc[tid] + pc[256 + tid];
    }
    gbar(bar, wg);

    // ===== P3: combine -> cur_att, write alignments, proj_to_decoder_in =====
    {
      if (tid < 16){
        int b = b0 + tid;
        float m0 = attM[b*4+0], m1 = attM[b*4+1], m2 = attM[b*4+2], m3 = attM[b*4+3];
        float m = fmaxf(fmaxf(m0, m1), fmaxf(m2, m3));
        float w0 = __expf(m0 - m), w1 = __expf(m1 - m), w2 = __expf(m2 - m), w3 = __expf(m3 - m);
        float Z = w0*attS[b*4+0] + w1*attS[b*4+1] + w2*attS[b*4+2] + w3*attS[b*4+3];
        float iZ = 1.f / Z;
        combL[tid*4+0] = w0*iZ; combL[tid*4+1] = w1*iZ;
        combL[tid*4+2] = w2*iZ; combL[tid*4+3] = w3*iZ;
      }
      __syncthreads();
      {
        int d = tid & 255, g2 = tid >> 8;
        #pragma unroll
        for (int r = 0; r < 8; ++r){
          int bb = g2 * 8 + r;
          int b = b0 + bb;
          float s = combL[bb*4+0]*attP[(b*4+0)*256+d] + combL[bb*4+1]*attP[(b*4+1)*256+d]
                  + combL[bb*4+2]*attP[(b*4+2)*256+d] + combL[bb*4+3]*attP[(b*4+3)*256+d];
          caL[bb * 260 + d] = s;
        }
      }
      __syncthreads();
      if (sl == 0){
        for (int r = tid; r < 4096; r += NTH){
          int bb = r >> 8, d = r & 255;
          cur[(b0 + bb) * 256 + d] = caL[bb * 260 + d];
        }
      } else if (sl == 1){
        for (int bb = 0; bb < 16; ++bb){
          int b = b0 + bb;
          float e = ews[b * 512 + tid];
          out[AOFF + (b * TDEC + t) * 512 + tid] = e * combL[bb * 4 + (tid >> 7)];
        }
      }
      {
        int dotid = tid >> 3, sg = tid & 7;
        int bb = dotid & 15, cc = dotid >> 4;
        int c = sl * 4 + cc, b = b0 + bb;
        const float* w = pjT + c * 512;
        float acc = 0.f;
        if (sg < 4){
          const float4* hp = (const float4*)(aHn + b * 256 + sg * 64);
          const float4* w4 = (const float4*)(w + sg * 64);
          #pragma unroll
          for (int i = 0; i < 16; ++i) acc += dot4(hp[i], w4[i]);
        } else {
          int k0 = (sg - 4) * 64;
          const float4* cp = (const float4*)(caL + bb * 260 + k0);
          const float4* w4 = (const float4*)(w + 256 + k0);
          #pragma unroll
          for (int i = 0; i < 16; ++i) acc += dot4(cp[i], w4[i]);
        }
        pp[dotid * 8 + sg] = acc;
      }
      __syncthreads();
      if (tid < 64){
        float s = 0.f;
        #pragma unroll
        for (int i = 0; i < 8; ++i) s += pp[tid * 8 + i];
        int c = sl * 4 + (tid >> 4);
        decin[(b0 + (tid & 15)) * 256 + c] = s + projB[c];
      }
    }
    gbar(bar, wg);

    // ===== P4: decoder GRU 1, d1 = h1' + dec_in =====
    {
      float acc = 0.f;
      if (x < 12){
        const float4* w4 = (const float4*)(wi1 + col * 256);
        const float4* xp = (const float4*)(decin + bb_ * 256);
        #pragma unroll
        for (int k = 0; k < 64; ++k) acc += dot4(xp[k], w4[k]);
        ewGi[cs * 16 + bq] = acc + d1Bi[col];
      } else if (x < 24){
        const float4* w4 = (const float4*)(wh1 + col * 256);
        const float4* hp = (const float4*)(h1a + p * 16384 + bb_ * 256);
        #pragma unroll
        for (int k = 0; k < 64; ++k) acc += dot4(hp[k], w4[k]);
        ewGh[cs * 16 + bq] = acc + d1Bh[col];
      }
      __syncthreads();
      if (tid < 64){
        int bt = tid & 15, jj = tid >> 4;
        int bbb = b0 + bt, j = sl * 4 + jj;
        float ir = ewGi[(jj*3+0)*16+bt] + ewGh[(jj*3+0)*16+bt];
        float iz = ewGi[(jj*3+1)*16+bt] + ewGh[(jj*3+1)*16+bt];
        float inn = ewGi[(jj*3+2)*16+bt];
        float hn  = ewGh[(jj*3+2)*16+bt];
        float r = fsig(ir), z = fsig(iz);
        float n = ftanh(inn + r * hn);
        float hv = h1a[p * 16384 + bbb * 256 + j];
        float hnew = (1.f - z) * n + z * hv;
        h1a[pn * 16384 + bbb * 256 + j] = hnew;
        d1v[bbb * 256 + j] = hnew + decin[bbb * 256 + j];
      }
    }
    gbar(bar, wg);

    // ===== P5: decoder GRU 2, d2 = h2' + d1  (flows into next P0, no barrier) =====
    {
      float acc = 0.f;
      if (x < 12){
        const float4* w4 = (const float4*)(wi2 + col * 256);
        const float4* xp = (const float4*)(d1v + bb_ * 256);
        #pragma unroll
        for (int k = 0; k < 64; ++k) acc += dot4(xp[k], w4[k]);
        ewGi[cs * 16 + bq] = acc + d2Bi[col];
      } else if (x < 24){
        const float4* w4 = (const float4*)(wh2 + col * 256);
        const float4* hp = (const float4*)(h2a + p * 16384 + bb_ * 256);
        #pragma unroll
        for (int k = 0; k < 64; ++k) acc += dot4(hp[k], w4[k]);
        ewGh[cs * 16 + bq] = acc + d2Bh[col];
      }
      __syncthreads();
      if (tid < 64){
        int bt = tid & 15, jj = tid >> 4;
        int bbb = b0 + bt, j = sl * 4 + jj;
        float ir = ewGi[(jj*3+0)*16+bt] + ewGh[(jj*3+0)*16+bt];
        float iz = ewGi[(jj*3+1)*16+bt] + ewGh[(jj*3+1)*16+bt];
        float inn = ewGi[(jj*3+2)*16+bt];
        float hn  = ewGh[(jj*3+2)*16+bt];
        float r = fsig(ir), z = fsig(iz);
        float n = ftanh(inn + r * hn);
        float hv = h2a[p * 16384 + bbb * 256 + j];
        float hnew = (1.f - z) * n + z * hv;
        h2a[pn * 16384 + bbb * 256 + j] = hnew;
        d2a[t * 16384 + j * 64 + bbb] = hnew + d1v[bbb * 256 + j];
      }
      __syncthreads();  // protect ew arrays from next iteration's P0 writes
    }
  }
}

// ---------------- deferred mel/gate heads over stored d2 ----------------
__global__ __launch_bounds__(NTH, 1) void outproj_k(const float* __restrict__ ws,
    float* __restrict__ out, const float* __restrict__ melW, const float* __restrict__ melB,
    const float* __restrict__ gateW, const float* __restrict__ gateB){
  int t = blockIdx.x, tid = threadIdx.x;
  int cx = tid & 255, bh = tid >> 8;
  const float* src = ws + OFF_D2 + t * 16384 + bh * 32;
  float acc[32];
  #pragma unroll
  for (int i = 0; i < 32; ++i) acc[i] = 0.f;
  bool ismel = (cx < 160);
  bool isgate = (cx >= 160 && cx < 162);
  for (int j = 0; j < 256; ++j){
    float w = 0.f;
    if (ismel) w = melW[j * 160 + cx];
    else if (isgate) w = gateW[j * 2 + (cx - 160)];
    const float4* dp = (const float4*)(src + j * 64);
    float4 vv[8];
    #pragma unroll
    for (int q = 0; q < 8; ++q) vv[q] = dp[q];
    #pragma unroll
    for (int q = 0; q < 8; ++q){
      acc[q*4+0] += vv[q].x * w; acc[q*4+1] += vv[q].y * w;
      acc[q*4+2] += vv[q].z * w; acc[q*4+3] += vv[q].w * w;
    }
  }
  if (ismel){
    float bb = melB[cx];
    #pragma unroll
    for (int i = 0; i < 32; ++i){
      int b = bh * 32 + i;
      out[(b * TDEC + t) * 160 + cx] = acc[i] + bb;
    }
  } else if (isgate){
    int g = cx - 160;
    float bb = gateB[g];
    #pragma unroll
    for (int i = 0; i < 32; ++i){
      int b = bh * 32 + i;
      out[GOFF + (b * TDEC + t) * 2 + g] = fsig(acc[i] + bb);
    }
  }
}

extern "C" void kernel_launch(void* const* d_in, const int* in_sizes, int n_in,
                              void* d_out, int out_size, void* d_ws, size_t ws_size,
                              hipStream_t stream)
{
  (void)in_sizes; (void)n_in; (void)out_size; (void)ws_size;
  const float* enc   = (const float*)d_in[0];
  const float* inp   = (const float*)d_in[1];
  const int*   mlen  = (const int*)d_in[2];
  const float* preW1 = (const float*)d_in[3];
  const float* preB1 = (const float*)d_in[4];
  const float* preW2 = (const float*)d_in[5];
  const float* preB2 = (const float*)d_in[6];
  const float* memW  = (const float*)d_in[7];
  const float* qW    = (const float*)d_in[8];
  const float* vW    = (const float*)d_in[9];
  const float* attWi = (const float*)d_in[10];
  const float* attWh = (const float*)d_in[11];
  const float* attBi = (const float*)d_in[12];
  const float* attBh = (const float*)d_in[13];
  const float* projW = (const float*)d_in[14];
  const float* projB = (const float*)d_in[15];
  const float* d1Wi  = (const float*)d_in[16];
  const float* d1Wh  = (const float*)d_in[17];
  const float* d1Bi  = (const float*)d_in[18];
  const float* d1Bh  = (const float*)d_in[19];
  const float* d2Wi  = (const float*)d_in[20];
  const float* d2Wh  = (const float*)d_in[21];
  const float* d2Bi  = (const float*)d_in[22];
  const float* d2Bh  = (const float*)d_in[23];
  const float* melW  = (const float*)d_in[24];
  const float* melB  = (const float*)d_in[25];
  const float* gateW = (const float*)d_in[26];
  const float* gateB = (const float*)d_in[27];
  float* ws = (float*)d_ws;
  float* out = (float*)d_out;

  // zero barrier + recurrent state (att_h, h1, h2 double-buffers, cur_att)
  hipMemsetAsync(d_ws, 0, (size_t)MEMSET_FLOATS * sizeof(float), stream);

  dim3 tt(256);
  transpose_k<<<dim3(24, 12), tt, 0, stream>>>(attWi, ws + OFF_WIT_A, 384, 768);
  transpose_k<<<dim3(24, 8),  tt, 0, stream>>>(attWh, ws + OFF_WHT_A, 256, 768);
  transpose_k<<<dim3(24, 8),  tt, 0, stream>>>(d1Wi,  ws + OFF_WIT_1, 256, 768);
  transpose_k<<<dim3(24, 8),  tt, 0, stream>>>(d1Wh,  ws + OFF_WHT_1, 256, 768);
  transpose_k<<<dim3(24, 8),  tt, 0, stream>>>(d2Wi,  ws + OFF_WIT_2, 256, 768);
  transpose_k<<<dim3(24, 8),  tt, 0, stream>>>(d2Wh,  ws + OFF_WHT_2, 256, 768);
  transpose_k<<<dim3(8, 16),  tt, 0, stream>>>(projW, ws + OFF_PROJT, 512, 256);
  transpose_k<<<dim3(8, 8),   tt, 0, stream>>>(qW,    ws + OFF_QWT,   256, 256);

  prenet_k<<<dim3(TDEC, 2), NTH, 0, stream>>>(ws, inp, preW1, preB1, preW2, preB2);
  pm_k<<<512, NTH, 0, stream>>>(ws, enc, memW);
  decoder_k<<<NWG, NTH, 0, stream>>>(ws, out, enc, mlen, vW, attBi, attBh, projB,
                                     d1Bi, d1Bh, d2Bi, d2Bh);
  outproj_k<<<TDEC, NTH, 0, stream>>>(ws, out, melW, melB, gateW, gateB);
}

// Round 2
// 22767.564 us; speedup vs baseline: 2.0136x; 2.0136x over previous
//
#include <hip/hip_runtime.h>

#define TDEC 400
#define NTH 512
#define NWG 256

typedef float f32x4 __attribute__((ext_vector_type(4)));
typedef unsigned u32x4 __attribute__((ext_vector_type(4)));
typedef unsigned u32x2 __attribute__((ext_vector_type(2)));

// ---------------- ws layout (float offsets) ----------------
#define OFF_BAR   0
#define OFF_ATTH  11264
#define OFF_H1    44032
#define OFF_H2    76800
#define OFF_CURP  109568
#define OFF_ATTS  125952
#define ZERO_FLOATS 126208
#define OFF_Q     126208
#define OFF_DECIN 142592
#define OFF_D1    158976
#define OFF_SUMS  175360
#define OFF_PRE   200960
#define OFF_PMB   3477760      /* bf16 [64][512][256] */
#define OFF_ENCB  7672064      /* bf16 [64][512][256] */
#define OFF_D2A   11866368     /* fp32 [400][256][64] */
#define OFF_WIT_A 18419968
#define OFF_WHT_A 18714880
#define OFF_WIT_1 18911488
#define OFF_WHT_1 19108096
#define OFF_WIT_2 19304704
#define OFF_WHT_2 19501312
#define OFF_PROJT 19697920
#define OFF_QWT   19828992
// total 19,894,528 floats = 79.6 MB

#define AOFF 4096000
#define GOFF 17203200

#define MSTI  (8*1024)
#define GENI  (9*1024)
#define FAILI (10*1024)

__device__ __forceinline__ float fsig(float x){ return 1.0f/(1.0f+__expf(-x)); }
__device__ __forceinline__ float ftanh(float x){ float e = __expf(2.0f*x); return 1.0f - 2.0f/(e+1.0f); }
__device__ __forceinline__ float dotv(f32x4 a, f32x4 b){ f32x4 p = a*b; return p[0]+p[1]+p[2]+p[3]; }

// ---- coherent (IC-serialized) access helpers: sc0 sc1 bypass L1/L2 ----
__device__ __forceinline__ f32x4 cload16(const float* p){
  f32x4 r;
  asm volatile("global_load_dwordx4 %0, %1, off sc0 sc1" : "=v"(r) : "v"(p));
  return r;
}
__device__ __forceinline__ f32x4 cload16w(const float* p){
  f32x4 r;
  asm volatile("global_load_dwordx4 %0, %1, off sc0 sc1\n\ts_waitcnt vmcnt(0)" : "=v"(r) : "v"(p));
  return r;
}
__device__ __forceinline__ float aload4(const float* p){
  unsigned u = __hip_atomic_load((const unsigned*)p, __ATOMIC_RELAXED, __HIP_MEMORY_SCOPE_AGENT);
  return __uint_as_float(u);
}
__device__ __forceinline__ void astore4(float* p, float v){
  __hip_atomic_store((unsigned*)p, __float_as_uint(v), __ATOMIC_RELAXED, __HIP_MEMORY_SCOPE_AGENT);
}
__device__ __forceinline__ void aadd(float* p, float v){
  __hip_atomic_fetch_add(p, v, __ATOMIC_RELAXED, __HIP_MEMORY_SCOPE_AGENT);
}
__device__ __forceinline__ int aloadi(const int* p){
  return __hip_atomic_load(p, __ATOMIC_RELAXED, __HIP_MEMORY_SCOPE_AGENT);
}

// gather 16 rows x 256 floats (row stride 256) -> LDS (row stride LSTR), coherent
template<int LSTR>
__device__ __forceinline__ void gat16x256(float* ld, const float* g){
  int i0 = threadIdx.x, i1 = threadIdx.x + 512;
  int r0 = i0>>6, c0 = (i0&63)<<2, r1 = i1>>6, c1 = (i1&63)<<2;
  f32x4 a = cload16(g + (r0<<8) + c0);
  f32x4 b = cload16(g + (r1<<8) + c1);
  asm volatile("s_waitcnt vmcnt(0)" : "+v"(a), "+v"(b));
  *(f32x4*)(ld + r0*LSTR + c0) = a;
  *(f32x4*)(ld + r1*LSTR + c1) = b;
}
// scaled variant: ld[r][coff+c] = g[r][c] * sL[r]
template<int LSTR>
__device__ __forceinline__ void gat16x256s(float* ld, const float* g, const float* sL, int coff){
  int i0 = threadIdx.x, i1 = threadIdx.x + 512;
  int r0 = i0>>6, c0 = (i0&63)<<2, r1 = i1>>6, c1 = (i1&63)<<2;
  f32x4 a = cload16(g + (r0<<8) + c0);
  f32x4 b = cload16(g + (r1<<8) + c1);
  asm volatile("s_waitcnt vmcnt(0)" : "+v"(a), "+v"(b));
  a *= sL[r0]; b *= sL[r1];
  *(f32x4*)(ld + r0*LSTR + coff + c0) = a;
  *(f32x4*)(ld + r1*LSTR + coff + c1) = b;
}

// fence-free grid barrier: monotonic counters, relaxed agent atomics only.
__device__ __forceinline__ void gbar(int* bar, int wg, int n){
  asm volatile("s_waitcnt vmcnt(0)" ::: "memory");
  __syncthreads();
  if (threadIdx.x == 0){
    if (aloadi(&bar[FAILI]) == 0){
      int a = __hip_atomic_fetch_add(&bar[(wg&7)*1024], 1, __ATOMIC_RELAXED, __HIP_MEMORY_SCOPE_AGENT);
      if (a == 32*n - 1){
        int m = __hip_atomic_fetch_add(&bar[MSTI], 1, __ATOMIC_RELAXED, __HIP_MEMORY_SCOPE_AGENT);
        if (m == 8*n - 1)
          __hip_atomic_store(&bar[GENI], n, __ATOMIC_RELAXED, __HIP_MEMORY_SCOPE_AGENT);
      }
      int sp = 0;
      while (aloadi(&bar[GENI]) < n){
        __builtin_amdgcn_s_sleep(1);
        if (++sp > (1<<20)){
          __hip_atomic_store(&bar[FAILI], 1, __ATOMIC_RELAXED, __HIP_MEMORY_SCOPE_AGENT);
          break;
        }
      }
    }
  }
  __syncthreads();
}

__device__ __forceinline__ unsigned short f2bf(float f){
  unsigned u = __float_as_uint(f);
  return (unsigned short)((u + 0x7fffu + ((u>>16)&1u)) >> 16);
}
__device__ __forceinline__ float bf2f(unsigned short s){
  return __uint_as_float(((unsigned)s) << 16);
}

// ---------------- generic 32x32 tiled transpose ----------------
__global__ __launch_bounds__(256, 1) void transpose_k(const float* __restrict__ in,
                                                      float* __restrict__ outp, int K, int C){
  __shared__ float tl[32][33];
  int c0 = blockIdx.x * 32, k0 = blockIdx.y * 32;
  int tx = threadIdx.x & 31, ty = threadIdx.x >> 5;
  for (int i = ty; i < 32; i += 8){
    int k = k0 + i, c = c0 + tx;
    if (k < K && c < C) tl[i][tx] = in[k * C + c];
  }
  __syncthreads();
  for (int i = ty; i < 32; i += 8){
    int c = c0 + i, k = k0 + tx;
    if (c < C && k < K) outp[c * K + k] = tl[tx][i];
  }
}

// ---------------- prenet (unchanged math) ----------------
__global__ __launch_bounds__(NTH, 1) void prenet_k(float* __restrict__ ws,
    const float* __restrict__ inp, const float* __restrict__ W1, const float* __restrict__ B1,
    const float* __restrict__ W2, const float* __restrict__ B2){
  __shared__ float xT[160 * 33];
  __shared__ float hT[256 * 33];
  int t = blockIdx.x, half = blockIdx.y, tid = threadIdx.x;
  int bbase = half * 32;
  for (int r = tid; r < 32 * 160; r += NTH){
    int b2 = r / 160; int k = r - b2 * 160;
    xT[k * 33 + b2] = (t == 0) ? 0.f : inp[((bbase + b2) * TDEC + (t - 1)) * 160 + k];
  }
  __syncthreads();
  int bl = tid & 31, slot = tid >> 5;
  float acc1[16];
  #pragma unroll
  for (int i = 0; i < 16; ++i) acc1[i] = 0.f;
  for (int k = 0; k < 160; ++k){
    float xv = xT[k * 33 + bl];
    const float* wr = W1 + k * 256 + slot * 16;
    #pragma unroll
    for (int i = 0; i < 16; ++i) acc1[i] += xv * wr[i];
  }
  #pragma unroll
  for (int i = 0; i < 16; ++i){
    int c = slot * 16 + i;
    hT[c * 33 + bl] = fmaxf(acc1[i] + B1[c], 0.f);
  }
  __syncthreads();
  float acc2[8];
  #pragma unroll
  for (int i = 0; i < 8; ++i) acc2[i] = 0.f;
  for (int k = 0; k < 256; ++k){
    float hv = hT[k * 33 + bl];
    const float* wr = W2 + k * 128 + slot * 8;
    #pragma unroll
    for (int i = 0; i < 8; ++i) acc2[i] += hv * wr[i];
  }
  float* dst = ws + OFF_PRE + t * 8192 + (bbase + bl) * 128 + slot * 8;
  #pragma unroll
  for (int i = 0; i < 8; ++i) dst[i] = fmaxf(acc2[i] + B2[slot * 8 + i], 0.f);
}

// ---------------- processed_memory (bf16 out) + enc bf16 copy ----------------
__global__ __launch_bounds__(NTH, 1) void pm_k(float* __restrict__ ws,
    const float* __restrict__ enc, const float* __restrict__ memW){
  int wg = blockIdx.x, tid = threadIdx.x;
  int b = wg & 63, th = wg >> 6;
  int slot = tid & 7, tt = tid >> 3;
  int trow = th * 64 + tt;
  const float* er = enc + ((size_t)(b * 512 + trow)) * 256;
  f32x4 acc[8];
  #pragma unroll
  for (int i = 0; i < 8; ++i) acc[i] = 0.f;
  for (int k = 0; k < 256; ++k){
    float ev = er[k];
    const f32x4* wr = (const f32x4*)(memW + k * 256 + slot * 32);
    #pragma unroll
    for (int i = 0; i < 8; ++i) acc[i] += ev * wr[i];
  }
  unsigned short* pmB = (unsigned short*)(ws + OFF_PMB);
  unsigned short* dst = pmB + ((size_t)(b * 512 + trow)) * 256 + slot * 32;
  #pragma unroll
  for (int i = 0; i < 8; ++i){
    u32x2 pk;
    pk[0] = (unsigned)f2bf(acc[i][0]) | ((unsigned)f2bf(acc[i][1]) << 16);
    pk[1] = (unsigned)f2bf(acc[i][2]) | ((unsigned)f2bf(acc[i][3]) << 16);
    *(u32x2*)(dst + i * 4) = pk;
  }
  // enc -> bf16 copy (same tile)
  const float* e2 = enc + ((size_t)(b * 512 + th * 64)) * 256;
  unsigned* eb = (unsigned*)((unsigned short*)(ws + OFF_ENCB) + ((size_t)(b * 512 + th * 64)) * 256);
  for (int i = tid; i < 64 * 128; i += NTH){
    float v0 = e2[i * 2], v1 = e2[i * 2 + 1];
    eb[i] = (unsigned)f2bf(v0) | ((unsigned)f2bf(v1) << 16);
  }
}

// ---------------- persistent recurrent decoder ----------------
__global__ __launch_bounds__(NTH, 1) void decoder_k(
    float* __restrict__ ws, float* __restrict__ out,
    const int* __restrict__ memlen,
    const float* __restrict__ vW,
    const float* __restrict__ attBi, const float* __restrict__ attBh,
    const float* __restrict__ projB,
    const float* __restrict__ d1Bi, const float* __restrict__ d1Bh,
    const float* __restrict__ d2Bi, const float* __restrict__ d2Bh)
{
  const int wg = blockIdx.x, tid = threadIdx.x;
  int* bar = (int*)ws;
  float* attH = ws + OFF_ATTH;       // [2][64][256]
  float* h1a  = ws + OFF_H1;
  float* h2a  = ws + OFF_H2;
  float* curP = ws + OFF_CURP;       // [64][256] atomic accumulated
  float* attS = ws + OFF_ATTS;       // [64]
  float* qarr = ws + OFF_Q;          // [64][256]
  float* decin= ws + OFF_DECIN;
  float* d1v  = ws + OFF_D1;
  const float* preB = ws + OFF_PRE;
  const unsigned short* pmB  = (const unsigned short*)(ws + OFF_PMB);
  const unsigned short* encB = (const unsigned short*)(ws + OFF_ENCB);
  float* d2a  = ws + OFF_D2A;
  const float* wiA = ws + OFF_WIT_A;
  const float* whA = ws + OFF_WHT_A;
  const float* wi1 = ws + OFF_WIT_1;
  const float* wh1 = ws + OFF_WHT_1;
  const float* wi2 = ws + OFF_WIT_2;
  const float* wh2 = ws + OFF_WHT_2;
  const float* pjT = ws + OFF_PROJT;
  const float* qWT = ws + OFF_QWT;

  __shared__ float xL[16 * 388];
  __shared__ float hL[16 * 260];
  __shared__ float ewGi[192], ewGh[192];
  __shared__ float dA[64];           // decinA persists P1 -> P3
  __shared__ float sL[16];
  __shared__ float red[512];
  __shared__ float qL[256], vL[256];
  __shared__ float psc[512], eL[128], pcL[512];

  if (tid < 256) vL[tid] = vW[tid];

  const int bg = wg & 3, sl = wg >> 2;
  const int b0 = bg << 4;
  const int b2 = wg & 63, ch2 = wg >> 6;
  const int len2 = memlen[b2];

  const int bq = tid & 15, x = tid >> 4;
  const int cs = (x >= 12) ? (x - 12) : x;
  const int gg = cs % 3, jh = cs / 3;
  const int col = gg * 256 + sl * 4 + jh;

  int bn = 0;
  for (int t = 0; t < TDEC; ++t){
    const int w = t & 1, r = w ^ 1;

    // ===== P0: attention GRU =====
    {
      if (tid < 16){ float s = aload4(attS + b0 + tid); sL[tid] = (s > 0.f) ? 1.f/s : 0.f; }
      gat16x256<260>(hL, attH + r * 16384 + b0 * 256);
      { int rr = tid >> 5, c = (tid & 31) << 2;
        *(f32x4*)(xL + rr * 388 + c) = *(const f32x4*)(preB + t * 8192 + (b0 + rr) * 128 + c); }
      __syncthreads();
      gat16x256s<388>(xL, curP + b0 * 256, sL, 128);
      __syncthreads();
      float acc = 0.f;
      if (x < 12){
        const f32x4* w4 = (const f32x4*)(wiA + col * 384);
        const f32x4* xp = (const f32x4*)(xL + bq * 388);
        #pragma unroll
        for (int k = 0; k < 96; ++k) acc += dotv(xp[k], w4[k]);
        ewGi[cs * 16 + bq] = acc + attBi[col];
      } else if (x < 24){
        const f32x4* w4 = (const f32x4*)(whA + col * 256);
        const f32x4* hp = (const f32x4*)(hL + bq * 260);
        #pragma unroll
        for (int k = 0; k < 64; ++k) acc += dotv(hp[k], w4[k]);
        ewGh[cs * 16 + bq] = acc + attBh[col];
      }
      __syncthreads();
      if (tid < 64){
        int bt = tid & 15, jj = tid >> 4;
        int j = sl * 4 + jj, bbb = b0 + bt;
        float ir = ewGi[(jj*3+0)*16+bt] + ewGh[(jj*3+0)*16+bt];
        float iz = ewGi[(jj*3+1)*16+bt] + ewGh[(jj*3+1)*16+bt];
        float inn = ewGi[(jj*3+2)*16+bt];
        float hn  = ewGh[(jj*3+2)*16+bt];
        float rg = fsig(ir), z = fsig(iz);
        float n = ftanh(inn + rg * hn);
        float h = hL[bt * 260 + j];
        astore4(attH + w * 16384 + bbb * 256 + j, (1.f - z) * n + z * h);
      }
    }
    gbar(bar, wg, ++bn);

    // ===== P1: q = att_h'@qW, decinA = att_h'@projW[:256], zero accumulators =====
    {
      gat16x256<260>(hL, attH + w * 16384 + b0 * 256);
      __syncthreads();
      {
        int dotid = tid >> 3, sg = tid & 7;
        int bq2 = dotid & 15, dd = dotid >> 4, d = sl * 4 + dd;
        const f32x4* hp = (const f32x4*)(hL + bq2 * 260 + sg * 32);
        const f32x4* w4 = (const f32x4*)(qWT + d * 256 + sg * 32);
        float acc = 0.f;
        #pragma unroll
        for (int k = 0; k < 8; ++k) acc += dotv(hp[k], w4[k]);
        red[dotid * 8 + sg] = acc;
      }
      __syncthreads();
      if (tid < 64){
        float s = 0.f;
        #pragma unroll
        for (int i = 0; i < 8; ++i) s += red[tid * 8 + i];
        astore4(qarr + (b0 + (tid & 15)) * 256 + sl * 4 + (tid >> 4), s);
      }
      __syncthreads();
      {
        int dotid = tid >> 3, sg = tid & 7;
        int bq2 = dotid & 15, cc = dotid >> 4, c = sl * 4 + cc;
        const f32x4* hp = (const f32x4*)(hL + bq2 * 260 + sg * 32);
        const f32x4* w4 = (const f32x4*)(pjT + c * 512 + sg * 32);
        float acc = 0.f;
        #pragma unroll
        for (int k = 0; k < 8; ++k) acc += dotv(hp[k], w4[k]);
        red[dotid * 8 + sg] = acc;
      }
      __syncthreads();
      if (tid < 64){
        float s = 0.f;
        #pragma unroll
        for (int i = 0; i < 8; ++i) s += red[tid * 8 + i];
        dA[(tid & 15) * 4 + (tid >> 4)] = s;
      }
      if (tid < 64) astore4(curP + wg * 64 + tid, 0.f);
      if (wg == 0 && tid < 64) astore4(attS + tid, 0.f);
    }
    gbar(bar, wg, ++bn);

    // ===== P2: scoring + exp + partial sum/context (no max pass; scores bounded) =====
    {
      if (tid < 64) *(f32x4*)(qL + tid * 4) = cload16w(qarr + b2 * 256 + tid * 4);
      __syncthreads();
      int te = tid >> 2, part = tid & 3;
      int ge = ch2 * 128 + te;
      float a4 = 0.f;
      if (ge < len2){
        const u32x4* pmp = (const u32x4*)(pmB + ((size_t)(b2 * 512 + ge)) * 256 + part * 64);
        #pragma unroll
        for (int i = 0; i < 8; ++i){
          u32x4 u = pmp[i];
          int kb = part * 64 + i * 8;
          a4 += ftanh(__uint_as_float(u[0] << 16)        + qL[kb+0]) * vL[kb+0];
          a4 += ftanh(__uint_as_float(u[0] & 0xFFFF0000u)+ qL[kb+1]) * vL[kb+1];
          a4 += ftanh(__uint_as_float(u[1] << 16)        + qL[kb+2]) * vL[kb+2];
          a4 += ftanh(__uint_as_float(u[1] & 0xFFFF0000u)+ qL[kb+3]) * vL[kb+3];
          a4 += ftanh(__uint_as_float(u[2] << 16)        + qL[kb+4]) * vL[kb+4];
          a4 += ftanh(__uint_as_float(u[2] & 0xFFFF0000u)+ qL[kb+5]) * vL[kb+5];
          a4 += ftanh(__uint_as_float(u[3] << 16)        + qL[kb+6]) * vL[kb+6];
          a4 += ftanh(__uint_as_float(u[3] & 0xFFFF0000u)+ qL[kb+7]) * vL[kb+7];
        }
      }
      psc[te * 4 + part] = a4;
      __syncthreads();
      if (tid < 128){
        float e = 0.f;
        if (ch2 * 128 + tid < len2)
          e = __expf(psc[tid*4+0] + psc[tid*4+1] + psc[tid*4+2] + psc[tid*4+3]);
        eL[tid] = e;
        out[AOFF + ((size_t)(b2 * TDEC + t)) * 512 + ch2 * 128 + tid] = e;
      }
      __syncthreads();
      if (tid < 64){
        float s = eL[tid] + eL[tid + 64];
        #pragma unroll
        for (int o = 32; o > 0; o >>= 1) s += __shfl_down(s, o);
        if (tid == 0) aadd(attS + b2, s);
      }
      {
        int d = tid & 255, hf = tid >> 8;
        const unsigned short* ep = encB + ((size_t)(b2 * 512 + ch2 * 128 + hf * 64)) * 256 + d;
        float acc = 0.f;
        #pragma unroll 8
        for (int i = 0; i < 64; ++i) acc += eL[hf * 64 + i] * bf2f(ep[i * 256]);
        pcL[tid] = acc;
      }
      __syncthreads();
      if (tid < 256) aadd(curP + b2 * 256 + tid, pcL[tid] + pcL[tid + 256]);
    }
    gbar(bar, wg, ++bn);

    // ===== P3: decin = decinA + cur_att@projW[256:] + b; record sums =====
    {
      if (tid < 16){ float s = aload4(attS + b0 + tid); sL[tid] = (s > 0.f) ? 1.f/s : 0.f; }
      __syncthreads();
      gat16x256s<388>(xL, curP + b0 * 256, sL, 0);
      __syncthreads();
      {
        int dotid = tid >> 3, sg = tid & 7;
        int bq2 = dotid & 15, cc = dotid >> 4, c = sl * 4 + cc;
        const f32x4* cp = (const f32x4*)(xL + bq2 * 388 + sg * 32);
        const f32x4* w4 = (const f32x4*)(pjT + c * 512 + 256 + sg * 32);
        float acc = 0.f;
        #pragma unroll
        for (int k = 0; k < 8; ++k) acc += dotv(cp[k], w4[k]);
        red[dotid * 8 + sg] = acc;
      }
      __syncthreads();
      if (tid < 64){
        float s = 0.f;
        #pragma unroll
        for (int i = 0; i < 8; ++i) s += red[tid * 8 + i];
        int bt = tid & 15, cc = tid >> 4, c = sl * 4 + cc;
        astore4(decin + (b0 + bt) * 256 + c, s + dA[bt * 4 + cc] + projB[c]);
      }
      if (wg < 4 && tid < 16)
        ws[OFF_SUMS + t * 64 + b0 + tid] = aload4(attS + b0 + tid);
    }
    gbar(bar, wg, ++bn);

    // ===== P4: decoder GRU 1; d1 = h1' + decin =====
    {
      gat16x256<388>(xL, decin + b0 * 256);
      gat16x256<260>(hL, h1a + r * 16384 + b0 * 256);
      __syncthreads();
      float acc = 0.f;
      if (x < 12){
        const f32x4* w4 = (const f32x4*)(wi1 + col * 256);
        const f32x4* xp = (const f32x4*)(xL + bq * 388);
        #pragma unroll
        for (int k = 0; k < 64; ++k) acc += dotv(xp[k], w4[k]);
        ewGi[cs * 16 + bq] = acc + d1Bi[col];
      } else if (x < 24){
        const f32x4* w4 = (const f32x4*)(wh1 + col * 256);
        const f32x4* hp = (const f32x4*)(hL + bq * 260);
        #pragma unroll
        for (int k = 0; k < 64; ++k) acc += dotv(hp[k], w4[k]);
        ewGh[cs * 16 + bq] = acc + d1Bh[col];
      }
      __syncthreads();
      if (tid < 64){
        int bt = tid & 15, jj = tid >> 4;
        int j = sl * 4 + jj, bbb = b0 + bt;
        float ir = ewGi[(jj*3+0)*16+bt] + ewGh[(jj*3+0)*16+bt];
        float iz = ewGi[(jj*3+1)*16+bt] + ewGh[(jj*3+1)*16+bt];
        float inn = ewGi[(jj*3+2)*16+bt];
        float hn  = ewGh[(jj*3+2)*16+bt];
        float rg = fsig(ir), z = fsig(iz);
        float n = ftanh(inn + rg * hn);
        float hv = hL[bt * 260 + j];
        float hnew = (1.f - z) * n + z * hv;
        astore4(h1a + w * 16384 + bbb * 256 + j, hnew);
        astore4(d1v + bbb * 256 + j, hnew + xL[bt * 388 + j]);
      }
    }
    gbar(bar, wg, ++bn);

    // ===== P5: decoder GRU 2; d2 = h2' + d1 (off critical path, no barrier) =====
    {
      gat16x256<388>(xL, d1v + b0 * 256);
      gat16x256<260>(hL, h2a + r * 16384 + b0 * 256);
      __syncthreads();
      float acc = 0.f;
      if (x < 12){
        const f32x4* w4 = (const f32x4*)(wi2 + col * 256);
        const f32x4* xp = (const f32x4*)(xL + bq * 388);
        #pragma unroll
        for (int k = 0; k < 64; ++k) acc += dotv(xp[k], w4[k]);
        ewGi[cs * 16 + bq] = acc + d2Bi[col];
      } else if (x < 24){
        const f32x4* w4 = (const f32x4*)(wh2 + col * 256);
        const f32x4* hp = (const f32x4*)(hL + bq * 260);
        #pragma unroll
        for (int k = 0; k < 64; ++k) acc += dotv(hp[k], w4[k]);
        ewGh[cs * 16 + bq] = acc + d2Bh[col];
      }
      __syncthreads();
      if (tid < 64){
        int bt = tid & 15, jj = tid >> 4;
        int j = sl * 4 + jj, bbb = b0 + bt;
        float ir = ewGi[(jj*3+0)*16+bt] + ewGh[(jj*3+0)*16+bt];
        float iz = ewGi[(jj*3+1)*16+bt] + ewGh[(jj*3+1)*16+bt];
        float inn = ewGi[(jj*3+2)*16+bt];
        float hn  = ewGh[(jj*3+2)*16+bt];
        float rg = fsig(ir), z = fsig(iz);
        float n = ftanh(inn + rg * hn);
        float hv = hL[bt * 260 + j];
        float hnew = (1.f - z) * n + z * hv;
        astore4(h2a + w * 16384 + bbb * 256 + j, hnew);
        d2a[t * 16384 + j * 64 + bbb] = hnew + xL[bt * 388 + j];
      }
      __syncthreads();  // protect LDS from next-iteration P0
    }
  }
}

// ---------------- alignment rescale: out_align *= 1/sum ----------------
__global__ __launch_bounds__(NTH, 1) void rescale_k(const float* __restrict__ ws,
                                                    float* __restrict__ out){
  int blk = blockIdx.x;             // b*TDEC + t
  int b = blk / TDEC, t = blk - b * TDEC;
  float s = ws[OFF_SUMS + t * 64 + b];
  float inv = (s > 0.f) ? 1.f / s : 0.f;
  out[AOFF + (size_t)blk * 512 + threadIdx.x] *= inv;
}

// ---------------- deferred mel/gate heads ----------------
__global__ __launch_bounds__(NTH, 1) void outproj_k(const float* __restrict__ ws,
    float* __restrict__ out, const float* __restrict__ melW, const float* __restrict__ melB,
    const float* __restrict__ gateW, const float* __restrict__ gateB){
  int t = blockIdx.x, tid = threadIdx.x;
  int cx = tid & 255, bh = tid >> 8;
  const float* src = ws + OFF_D2A + t * 16384 + bh * 32;
  float acc[32];
  #pragma unroll
  for (int i = 0; i < 32; ++i) acc[i] = 0.f;
  bool ismel = (cx < 160);
  bool isgate = (cx >= 160 && cx < 162);
  for (int j = 0; j < 256; ++j){
    float wv = 0.f;
    if (ismel) wv = melW[j * 160 + cx];
    else if (isgate) wv = gateW[j * 2 + (cx - 160)];
    const f32x4* dp = (const f32x4*)(src + j * 64);
    f32x4 vv[8];
    #pragma unroll
    for (int q = 0; q < 8; ++q) vv[q] = dp[q];
    #pragma unroll
    for (int q = 0; q < 8; ++q){
      acc[q*4+0] += vv[q][0] * wv; acc[q*4+1] += vv[q][1] * wv;
      acc[q*4+2] += vv[q][2] * wv; acc[q*4+3] += vv[q][3] * wv;
    }
  }
  if (ismel){
    float bb = melB[cx];
    #pragma unroll
    for (int i = 0; i < 32; ++i){
      int b = bh * 32 + i;
      out[((size_t)(b * TDEC + t)) * 160 + cx] = acc[i] + bb;
    }
  } else if (isgate){
    int g = cx - 160;
    float bb = gateB[g];
    #pragma unroll
    for (int i = 0; i < 32; ++i){
      int b = bh * 32 + i;
      out[GOFF + ((size_t)(b * TDEC + t)) * 2 + g] = fsig(acc[i] + bb);
    }
  }
}

extern "C" void kernel_launch(void* const* d_in, const int* in_sizes, int n_in,
                              void* d_out, int out_size, void* d_ws, size_t ws_size,
                              hipStream_t stream)
{
  (void)in_sizes; (void)n_in; (void)out_size; (void)ws_size;
  const float* enc   = (const float*)d_in[0];
  const float* inp   = (const float*)d_in[1];
  const int*   mlen  = (const int*)d_in[2];
  const float* preW1 = (const float*)d_in[3];
  const float* preB1 = (const float*)d_in[4];
  const float* preW2 = (const float*)d_in[5];
  const float* preB2 = (const float*)d_in[6];
  const float* memW  = (const float*)d_in[7];
  const float* qW    = (const float*)d_in[8];
  const float* vW    = (const float*)d_in[9];
  const float* attWi = (const float*)d_in[10];
  const float* attWh = (const float*)d_in[11];
  const float* attBi = (const float*)d_in[12];
  const float* attBh = (const float*)d_in[13];
  const float* projW = (const float*)d_in[14];
  const float* projB = (const float*)d_in[15];
  const float* d1Wi  = (const float*)d_in[16];
  const float* d1Wh  = (const float*)d_in[17];
  const float* d1Bi  = (const float*)d_in[18];
  const float* d1Bh  = (const float*)d_in[19];
  const float* d2Wi  = (const float*)d_in[20];
  const float* d2Wh  = (const float*)d_in[21];
  const float* d2Bi  = (const float*)d_in[22];
  const float* d2Bh  = (const float*)d_in[23];
  const float* melW  = (const float*)d_in[24];
  const float* melB  = (const float*)d_in[25];
  const float* gateW = (const float*)d_in[26];
  const float* gateB = (const float*)d_in[27];
  float* ws = (float*)d_ws;
  float* out = (float*)d_out;

  // zero barrier + recurrent state + accumulators
  hipMemsetAsync(d_ws, 0, (size_t)ZERO_FLOATS * sizeof(float), stream);

  dim3 tt(256);
  transpose_k<<<dim3(24, 12), tt, 0, stream>>>(attWi, ws + OFF_WIT_A, 384, 768);
  transpose_k<<<dim3(24, 8),  tt, 0, stream>>>(attWh, ws + OFF_WHT_A, 256, 768);
  transpose_k<<<dim3(24, 8),  tt, 0, stream>>>(d1Wi,  ws + OFF_WIT_1, 256, 768);
  transpose_k<<<dim3(24, 8),  tt, 0, stream>>>(d1Wh,  ws + OFF_WHT_1, 256, 768);
  transpose_k<<<dim3(24, 8),  tt, 0, stream>>>(d2Wi,  ws + OFF_WIT_2, 256, 768);
  transpose_k<<<dim3(24, 8),  tt, 0, stream>>>(d2Wh,  ws + OFF_WHT_2, 256, 768);
  transpose_k<<<dim3(8, 16),  tt, 0, stream>>>(projW, ws + OFF_PROJT, 512, 256);
  transpose_k<<<dim3(8, 8),   tt, 0, stream>>>(qW,    ws + OFF_QWT,   256, 256);

  prenet_k<<<dim3(TDEC, 2), NTH, 0, stream>>>(ws, inp, preW1, preB1, preW2, preB2);
  pm_k<<<512, NTH, 0, stream>>>(ws, enc, memW);
  decoder_k<<<NWG, NTH, 0, stream>>>(ws, out, mlen, vW, attBi, attBh, projB,
                                     d1Bi, d1Bh, d2Bi, d2Bh);
  rescale_k<<<64 * TDEC, NTH, 0, stream>>>(ws, out);
  outproj_k<<<TDEC, NTH, 0, stream>>>(ws, out, melW, melB, gateW, gateB);
}

// Round 3
// 16134.201 us; speedup vs baseline: 2.8415x; 1.4111x over previous
//
#include <hip/hip_runtime.h>

#define TDEC 400
#define NTH 512
#define NWG 256

typedef float f32x4 __attribute__((ext_vector_type(4)));
typedef unsigned u32x4 __attribute__((ext_vector_type(4)));
typedef unsigned u32x2 __attribute__((ext_vector_type(2)));

// ---------------- ws layout (float offsets) ----------------
#define OFF_BAR   0
#define OFF_ATTH  11264
#define OFF_H1    44032
#define OFF_H2    76800
#define OFF_CURP  109568
#define OFF_ATTS  125952
#define ZERO_FLOATS 126208
#define OFF_Q     126208
#define OFF_D1    142592
#define OFF_SUMS  158976
#define OFF_C1    184576
#define OFF_PRE   185600       /* bf16 [400][64][128] */
#define OFF_PMB   1824000      /* bf16 [64][512][256] */
#define OFF_ENCB  6018304      /* bf16 [64][512][256] */
#define OFF_D2A   10212608     /* fp32 [400][256][64]; setup overlays below */
#define T_WIT_A   10212608
#define T_WHT_A   10507520
#define T_M1T     10704128
#define T_WHT1    11097344
#define T_PJT     11293952
#define T_WIT2    11425024
#define T_WHT2    11621632
#define T_QWT     11818240
#define T_M1      11883776
#define OFF_BLOB  16766208     /* bf16: 64 slices x BLOB_STR */
// total 17,618,176 floats = 70.5 MB

#define BLOB_N   26112
#define BLOB_STR 26624
// blob section offsets (ushort units)
#define BO_AI  0
#define BO_AH  4608
#define BO_Q   7680
#define BO_M1  8704
#define BO_H1  14848
#define BO_PJ  17920
#define BO_I2  19968
#define BO_H2  23040

#define AOFF 4096000
#define GOFF 17203200

#define MSTI  (8*1024)
#define GENI  (9*1024)
#define FAILI (10*1024)

__device__ __forceinline__ float fsig(float x){ return 1.0f/(1.0f+__expf(-x)); }
__device__ __forceinline__ float ftanh(float x){ float e = __expf(2.0f*x); return 1.0f - 2.0f/(e+1.0f); }
__device__ __forceinline__ float dotv(f32x4 a, f32x4 b){ f32x4 p = a*b; return p[0]+p[1]+p[2]+p[3]; }
__device__ __forceinline__ float blo(unsigned u){ return __uint_as_float(u<<16); }
__device__ __forceinline__ float bhi(unsigned u){ return __uint_as_float(u & 0xffff0000u); }

__device__ __forceinline__ f32x4 cload16(const float* p){
  f32x4 r;
  asm volatile("global_load_dwordx4 %0, %1, off sc0 sc1" : "=v"(r) : "v"(p));
  return r;
}
__device__ __forceinline__ f32x4 cload16w(const float* p){
  f32x4 r;
  asm volatile("global_load_dwordx4 %0, %1, off sc0 sc1\n\ts_waitcnt vmcnt(0)" : "=v"(r) : "v"(p));
  return r;
}
__device__ __forceinline__ float aload4(const float* p){
  unsigned u = __hip_atomic_load((const unsigned*)p, __ATOMIC_RELAXED, __HIP_MEMORY_SCOPE_AGENT);
  return __uint_as_float(u);
}
__device__ __forceinline__ void astore4(float* p, float v){
  __hip_atomic_store((unsigned*)p, __float_as_uint(v), __ATOMIC_RELAXED, __HIP_MEMORY_SCOPE_AGENT);
}
__device__ __forceinline__ void aadd(float* p, float v){
  __hip_atomic_fetch_add(p, v, __ATOMIC_RELAXED, __HIP_MEMORY_SCOPE_AGENT);
}
__device__ __forceinline__ int aloadi(const int* p){
  return __hip_atomic_load(p, __ATOMIC_RELAXED, __HIP_MEMORY_SCOPE_AGENT);
}

// fence-free grid barrier: monotonic counters, relaxed agent atomics only.
__device__ __forceinline__ void gbar(int* bar, int wg, int n){
  asm volatile("s_waitcnt vmcnt(0)" ::: "memory");
  __syncthreads();
  if (threadIdx.x == 0){
    if (aloadi(&bar[FAILI]) == 0){
      int a = __hip_atomic_fetch_add(&bar[(wg&7)*1024], 1, __ATOMIC_RELAXED, __HIP_MEMORY_SCOPE_AGENT);
      if (a == 32*n - 1){
        int m = __hip_atomic_fetch_add(&bar[MSTI], 1, __ATOMIC_RELAXED, __HIP_MEMORY_SCOPE_AGENT);
        if (m == 8*n - 1)
          __hip_atomic_store(&bar[GENI], n, __ATOMIC_RELAXED, __HIP_MEMORY_SCOPE_AGENT);
      }
      int sp = 0;
      while (aloadi(&bar[GENI]) < n){
        __builtin_amdgcn_s_sleep(1);
        if (++sp > (1<<20)){
          __hip_atomic_store(&bar[FAILI], 1, __ATOMIC_RELAXED, __HIP_MEMORY_SCOPE_AGENT);
          break;
        }
      }
    }
  }
  __syncthreads();
}

__device__ __forceinline__ unsigned short f2bf(float f){
  unsigned u = __float_as_uint(f);
  return (unsigned short)((u + 0x7fffu + ((u>>16)&1u)) >> 16);
}

// bf16-weight dot: N8 groups of 8 (weights bf16 stream, x fp32 in LDS)
template<int N8>
__device__ __forceinline__ float bdot(const unsigned short* wr, const float* xr){
  float acc = 0.f;
  #pragma unroll 4
  for (int k = 0; k < N8; ++k){
    u32x4 u = *(const u32x4*)(wr + k*8);
    f32x4 a = *(const f32x4*)(xr + k*8);
    f32x4 b = *(const f32x4*)(xr + k*8 + 4);
    acc += blo(u[0])*a[0] + bhi(u[0])*a[1] + blo(u[1])*a[2] + bhi(u[1])*a[3]
         + blo(u[2])*b[0] + bhi(u[2])*b[1] + blo(u[3])*b[2] + bhi(u[3])*b[3];
  }
  return acc;
}

// ---------------- generic 32x32 tiled transpose ----------------
__global__ __launch_bounds__(256, 1) void transpose_k(const float* __restrict__ in,
                                                      float* __restrict__ outp, int K, int C){
  __shared__ float tl[32][33];
  int c0 = blockIdx.x * 32, k0 = blockIdx.y * 32;
  int tx = threadIdx.x & 31, ty = threadIdx.x >> 5;
  for (int i = ty; i < 32; i += 8){
    int k = k0 + i, c = c0 + tx;
    if (k < K && c < C) tl[i][tx] = in[k * C + c];
  }
  __syncthreads();
  for (int i = ty; i < 32; i += 8){
    int c = c0 + i, k = k0 + tx;
    if (c < C && k < K) outp[c * K + k] = tl[tx][i];
  }
}

// ---------------- M1 = projW @ d1Wi  (512x768) ----------------
__global__ __launch_bounds__(128, 1) void fuse_k(const float* __restrict__ projW,
    const float* __restrict__ d1Wi, float* __restrict__ M1){
  int jt = blockIdx.x % 6, i = blockIdx.x / 6;
  int j = jt * 128 + threadIdx.x;
  float acc = 0.f;
  for (int k = 0; k < 256; ++k) acc += projW[i*256+k] * d1Wi[k*768+j];
  M1[i*768+j] = acc;
}

// ---------------- c1 = projB @ d1Wi + d1Bi ----------------
__global__ __launch_bounds__(256, 1) void c1_k(const float* __restrict__ projB,
    const float* __restrict__ d1Wi, const float* __restrict__ d1Bi, float* __restrict__ C1){
  int j = blockIdx.x * 256 + threadIdx.x;
  float acc = d1Bi[j];
  for (int k = 0; k < 256; ++k) acc += projB[k] * d1Wi[k*768+j];
  C1[j] = acc;
}

// ---------------- pack per-sl bf16 weight blobs ----------------
__global__ __launch_bounds__(512, 1) void pack_k(float* __restrict__ ws){
  int sl = blockIdx.x;
  const float* TAI = ws + T_WIT_A;
  const float* TAH = ws + T_WHT_A;
  const float* TM1 = ws + T_M1T;
  const float* TH1 = ws + T_WHT1;
  const float* TPJ = ws + T_PJT;
  const float* TI2 = ws + T_WIT2;
  const float* TH2 = ws + T_WHT2;
  const float* TQ  = ws + T_QWT;
  unsigned short* blob = (unsigned short*)(ws + OFF_BLOB) + (size_t)sl * BLOB_STR;
  for (int idx = threadIdx.x; idx < BLOB_N; idx += 512){
    float v; int cs, k, o;
    if (idx < BO_AH){ cs = idx / 384; k = idx - cs*384;
      v = TAI[((cs%3)*256 + sl*4 + cs/3)*384 + k]; }
    else if (idx < BO_Q){ o = idx - BO_AH; cs = o >> 8; k = o & 255;
      v = TAH[((cs%3)*256 + sl*4 + cs/3)*256 + k]; }
    else if (idx < BO_M1){ o = idx - BO_Q; cs = o >> 8; k = o & 255;
      v = TQ[(sl*4 + cs)*256 + k]; }
    else if (idx < BO_H1){ o = idx - BO_M1; cs = o >> 9; k = o & 511;
      v = TM1[((cs%3)*256 + sl*4 + cs/3)*512 + k]; }
    else if (idx < BO_PJ){ o = idx - BO_H1; cs = o >> 8; k = o & 255;
      v = TH1[((cs%3)*256 + sl*4 + cs/3)*256 + k]; }
    else if (idx < BO_I2){ o = idx - BO_PJ; cs = o >> 9; k = o & 511;
      v = TPJ[(sl*4 + cs)*512 + k]; }
    else if (idx < BO_H2){ o = idx - BO_I2; cs = o >> 8; k = o & 255;
      v = TI2[((cs%3)*256 + sl*4 + cs/3)*256 + k]; }
    else { o = idx - BO_H2; cs = o >> 8; k = o & 255;
      v = TH2[((cs%3)*256 + sl*4 + cs/3)*256 + k]; }
    blob[idx] = f2bf(v);
  }
}

// ---------------- prenet: bf16 output ----------------
__global__ __launch_bounds__(NTH, 1) void prenet_k(float* __restrict__ ws,
    const float* __restrict__ inp, const float* __restrict__ W1, const float* __restrict__ B1,
    const float* __restrict__ W2, const float* __restrict__ B2){
  __shared__ float xT[160 * 33];
  __shared__ float hT[256 * 33];
  int t = blockIdx.x, half = blockIdx.y, tid = threadIdx.x;
  int bbase = half * 32;
  for (int r = tid; r < 32 * 160; r += NTH){
    int b2 = r / 160; int k = r - b2 * 160;
    xT[k * 33 + b2] = (t == 0) ? 0.f : inp[((bbase + b2) * TDEC + (t - 1)) * 160 + k];
  }
  __syncthreads();
  int bl = tid & 31, slot = tid >> 5;
  float acc1[16];
  #pragma unroll
  for (int i = 0; i < 16; ++i) acc1[i] = 0.f;
  for (int k = 0; k < 160; ++k){
    float xv = xT[k * 33 + bl];
    const float* wr = W1 + k * 256 + slot * 16;
    #pragma unroll
    for (int i = 0; i < 16; ++i) acc1[i] += xv * wr[i];
  }
  #pragma unroll
  for (int i = 0; i < 16; ++i){
    int c = slot * 16 + i;
    hT[c * 33 + bl] = fmaxf(acc1[i] + B1[c], 0.f);
  }
  __syncthreads();
  float acc2[8];
  #pragma unroll
  for (int i = 0; i < 8; ++i) acc2[i] = 0.f;
  for (int k = 0; k < 256; ++k){
    float hv = hT[k * 33 + bl];
    const float* wr = W2 + k * 128 + slot * 8;
    #pragma unroll
    for (int i = 0; i < 8; ++i) acc2[i] += hv * wr[i];
  }
  unsigned short* dst = (unsigned short*)(ws + OFF_PRE) + (size_t)t*8192 + (bbase + bl)*128 + slot*8;
  u32x4 pk;
  #pragma unroll
  for (int i = 0; i < 4; ++i){
    float v0 = fmaxf(acc2[2*i] + B2[slot*8 + 2*i], 0.f);
    float v1 = fmaxf(acc2[2*i+1] + B2[slot*8 + 2*i+1], 0.f);
    pk[i] = (unsigned)f2bf(v0) | ((unsigned)f2bf(v1) << 16);
  }
  *(u32x4*)dst = pk;
}

// ---------------- processed_memory (bf16) + enc bf16 copy ----------------
__global__ __launch_bounds__(NTH, 1) void pm_k(float* __restrict__ ws,
    const float* __restrict__ enc, const float* __restrict__ memW){
  int wg = blockIdx.x, tid = threadIdx.x;
  int b = wg & 63, th = wg >> 6;
  int slot = tid & 7, tt = tid >> 3;
  int trow = th * 64 + tt;
  const float* er = enc + ((size_t)(b * 512 + trow)) * 256;
  f32x4 acc[8];
  #pragma unroll
  for (int i = 0; i < 8; ++i) acc[i] = 0.f;
  for (int k = 0; k < 256; ++k){
    float ev = er[k];
    const f32x4* wr = (const f32x4*)(memW + k * 256 + slot * 32);
    #pragma unroll
    for (int i = 0; i < 8; ++i) acc[i] += ev * wr[i];
  }
  unsigned short* pmB = (unsigned short*)(ws + OFF_PMB);
  unsigned short* dst = pmB + ((size_t)(b * 512 + trow)) * 256 + slot * 32;
  #pragma unroll
  for (int i = 0; i < 8; ++i){
    u32x2 pk;
    pk[0] = (unsigned)f2bf(acc[i][0]) | ((unsigned)f2bf(acc[i][1]) << 16);
    pk[1] = (unsigned)f2bf(acc[i][2]) | ((unsigned)f2bf(acc[i][3]) << 16);
    *(u32x2*)(dst + i * 4) = pk;
  }
  const float* e2 = enc + ((size_t)(b * 512 + th * 64)) * 256;
  unsigned* eb = (unsigned*)((unsigned short*)(ws + OFF_ENCB) + ((size_t)(b * 512 + th * 64)) * 256);
  for (int i = tid; i < 64 * 128; i += NTH){
    float v0 = e2[i * 2], v1 = e2[i * 2 + 1];
    eb[i] = (unsigned)f2bf(v0) | ((unsigned)f2bf(v1) << 16);
  }
}

// ---------------- persistent recurrent decoder ----------------
__global__ __launch_bounds__(NTH, 1) void decoder_k(
    float* __restrict__ ws, float* __restrict__ out,
    const int* __restrict__ memlen,
    const float* __restrict__ vW,
    const float* __restrict__ attBi, const float* __restrict__ attBh,
    const float* __restrict__ projB,
    const float* __restrict__ d1Bh,
    const float* __restrict__ d2Bi, const float* __restrict__ d2Bh)
{
  const int wg = blockIdx.x, tid = threadIdx.x;
  int* bar = (int*)ws;
  float* attH = ws + OFF_ATTH;       // [2][64][256]
  float* h1a  = ws + OFF_H1;
  float* h2a  = ws + OFF_H2;
  float* curP = ws + OFF_CURP;       // [64][256] atomic accumulated (unnormalized ctx)
  float* attS = ws + OFF_ATTS;       // [64] exp-sums
  float* qarr = ws + OFF_Q;
  float* d1v  = ws + OFF_D1;
  const float* C1v = ws + OFF_C1;
  const unsigned short* preB16 = (const unsigned short*)(ws + OFF_PRE);
  const unsigned short* pmB  = (const unsigned short*)(ws + OFF_PMB);
  const unsigned short* encB = (const unsigned short*)(ws + OFF_ENCB);
  float* d2a  = ws + OFF_D2A;

  __shared__ float BUF[12416];
  __shared__ float qL[256], vL[256];
  __shared__ float psc[512], eL[128];
  __shared__ float red[512];
  __shared__ float ewGi[192], ewGh[192], pdec[128];

  if (tid < 256) vL[tid] = vW[tid];

  const int bg = wg & 3, sl = wg >> 2;
  const int b0 = bg << 4;
  const int b2 = wg & 63, ch2 = wg >> 6;
  const int len2 = memlen[b2];
  const unsigned short* blob = (const unsigned short*)(ws + OFF_BLOB) + (size_t)sl * BLOB_STR;

  const int bq = tid & 15, x = tid >> 4;
  const int cs = (x >= 12) ? (x - 12) : x;
  const int gg = cs % 3, jh = cs / 3;
  const int col = gg * 256 + sl * 4 + jh;

  const int r0 = tid >> 6, c0 = (tid & 63) << 2;   // gather mapping (rows 0..7 / 8..15)
  const int r1 = r0 + 8;

  int bn = 0;
  for (int t = 0; t < TDEC; ++t){
    const int w = t & 1, rb = w ^ 1;

    // ===== P0: attention GRU: h' = GRU(cat(pre, ctx_{t-1}), att_h) =====
    {
      float* xL = BUF;              // [16][388]: [0:128)=pre, [128:384)=ctx
      float* hL = BUF + 6208;       // [16][260]: att_h prev
      const float* gH = attH + rb * 16384 + b0 * 256;
      const float* gC = curP + b0 * 256;
      f32x4 vH0 = cload16(gH + (r0<<8) + c0), vH1 = cload16(gH + (r1<<8) + c0);
      f32x4 vC0 = cload16(gC + (r0<<8) + c0), vC1 = cload16(gC + (r1<<8) + c0);
      float s0 = aload4(attS + b0 + r0), s1 = aload4(attS + b0 + r1);
      if (tid < 256){
        int pr = tid >> 4, pc = (tid & 15) * 8;
        u32x4 u = *(const u32x4*)(preB16 + (size_t)t*8192 + (b0 + pr)*128 + pc);
        float* xd = xL + pr*388 + pc;
        xd[0]=blo(u[0]); xd[1]=bhi(u[0]); xd[2]=blo(u[1]); xd[3]=bhi(u[1]);
        xd[4]=blo(u[2]); xd[5]=bhi(u[2]); xd[6]=blo(u[3]); xd[7]=bhi(u[3]);
      }
      asm volatile("s_waitcnt vmcnt(0)" : "+v"(vH0),"+v"(vH1),"+v"(vC0),"+v"(vC1));
      float iv0 = s0 > 0.f ? 1.f/s0 : 0.f, iv1 = s1 > 0.f ? 1.f/s1 : 0.f;
      *(f32x4*)(hL + r0*260 + c0) = vH0; *(f32x4*)(hL + r1*260 + c0) = vH1;
      *(f32x4*)(xL + r0*388 + 128 + c0) = vC0*iv0; *(f32x4*)(xL + r1*388 + 128 + c0) = vC1*iv1;
      __syncthreads();
      if (x < 12)
        ewGi[cs*16 + bq] = bdot<48>(blob + BO_AI + cs*384, xL + bq*388) + attBi[col];
      else if (x < 24)
        ewGh[cs*16 + bq] = bdot<32>(blob + BO_AH + cs*256, hL + bq*260) + attBh[col];
      __syncthreads();
      if (tid < 64){
        int bt = tid & 15, jj = tid >> 4;
        int j = sl*4 + jj;
        float ir = ewGi[(jj*3+0)*16+bt] + ewGh[(jj*3+0)*16+bt];
        float iz = ewGi[(jj*3+1)*16+bt] + ewGh[(jj*3+1)*16+bt];
        float inn = ewGi[(jj*3+2)*16+bt];
        float hn  = ewGh[(jj*3+2)*16+bt];
        float rg = fsig(ir), z = fsig(iz);
        float n = ftanh(inn + rg * hn);
        float h = hL[bt*260 + j];
        astore4(attH + w*16384 + (b0+bt)*256 + j, (1.f - z)*n + z*h);
      }
    }
    gbar(bar, wg, ++bn);

    // ===== P1: q = att_h' @ qW; zero accumulators =====
    {
      float* aL = BUF;              // [16][260]
      const float* gA = attH + w*16384 + b0*256;
      f32x4 vA0 = cload16(gA + (r0<<8) + c0), vA1 = cload16(gA + (r1<<8) + c0);
      asm volatile("s_waitcnt vmcnt(0)" : "+v"(vA0),"+v"(vA1));
      *(f32x4*)(aL + r0*260 + c0) = vA0; *(f32x4*)(aL + r1*260 + c0) = vA1;
      __syncthreads();
      {
        int dotid = tid >> 3, sg = tid & 7;
        int bq2 = dotid & 15, dd = dotid >> 4;
        red[dotid*8 + sg] = bdot<4>(blob + BO_Q + dd*256 + sg*32, aL + bq2*260 + sg*32);
      }
      __syncthreads();
      if (tid < 64){
        float s = 0.f;
        #pragma unroll
        for (int i = 0; i < 8; ++i) s += red[tid*8 + i];
        astore4(qarr + (b0 + (tid & 15))*256 + sl*4 + (tid >> 4), s);
      }
      if (tid < 64) astore4(curP + wg*64 + tid, 0.f);
      if (wg == 0 && tid < 64) astore4(attS + tid, 0.f);
    }
    gbar(bar, wg, ++bn);

    // ===== P2: scoring + exp + partial sum/context =====
    {
      float* ctxP = BUF;            // [4096]
      if (tid < 64){
        f32x4 v = cload16w(qarr + b2*256 + tid*4);
        *(f32x4*)(qL + tid*4) = v;
      }
      __syncthreads();
      {
        int te = tid >> 2, part = tid & 3;
        int ge = ch2*128 + te;
        float a4 = 0.f;
        if (ge < len2){
          const u32x4* pmp = (const u32x4*)(pmB + ((size_t)(b2*512 + ge))*256 + part*64);
          #pragma unroll
          for (int i = 0; i < 8; ++i){
            u32x4 u = pmp[i];
            int kb = part*64 + i*8;
            a4 += ftanh(blo(u[0]) + qL[kb+0]) * vL[kb+0];
            a4 += ftanh(bhi(u[0]) + qL[kb+1]) * vL[kb+1];
            a4 += ftanh(blo(u[1]) + qL[kb+2]) * vL[kb+2];
            a4 += ftanh(bhi(u[1]) + qL[kb+3]) * vL[kb+3];
            a4 += ftanh(blo(u[2]) + qL[kb+4]) * vL[kb+4];
            a4 += ftanh(bhi(u[2]) + qL[kb+5]) * vL[kb+5];
            a4 += ftanh(blo(u[3]) + qL[kb+6]) * vL[kb+6];
            a4 += ftanh(bhi(u[3]) + qL[kb+7]) * vL[kb+7];
          }
        }
        psc[tid] = a4;
      }
      __syncthreads();
      if (tid < 128){
        float e = 0.f;
        if (ch2*128 + tid < len2)
          e = __expf(psc[tid*4+0] + psc[tid*4+1] + psc[tid*4+2] + psc[tid*4+3]);
        eL[tid] = e;
        out[AOFF + ((size_t)(b2*TDEC + t))*512 + ch2*128 + tid] = e;
      }
      __syncthreads();
      if (tid < 64){
        float s = eL[tid] + eL[tid + 64];
        #pragma unroll
        for (int o = 32; o > 0; o >>= 1) s += __shfl_down(s, o);
        if (tid == 0) aadd(attS + b2, s);
      }
      {
        int ich = tid >> 5, dblk = tid & 31;
        int rbase = ch2*128 + ich*8;
        f32x4 acA = 0.f, acB = 0.f;
        if (rbase < len2){
          const unsigned short* ep = encB + ((size_t)(b2*512 + rbase))*256 + dblk*8;
          #pragma unroll
          for (int i = 0; i < 8; ++i){
            u32x4 u = *(const u32x4*)(ep + i*256);
            float e = eL[ich*8 + i];
            acA[0] += e*blo(u[0]); acA[1] += e*bhi(u[0]);
            acA[2] += e*blo(u[1]); acA[3] += e*bhi(u[1]);
            acB[0] += e*blo(u[2]); acB[1] += e*bhi(u[2]);
            acB[2] += e*blo(u[3]); acB[3] += e*bhi(u[3]);
          }
        }
        *(f32x4*)(ctxP + tid*8) = acA;
        *(f32x4*)(ctxP + tid*8 + 4) = acB;
      }
      __syncthreads();
      if (tid < 256){
        int dblk = tid >> 3, d = tid & 7;
        float s = 0.f;
        #pragma unroll
        for (int i = 0; i < 16; ++i) s += ctxP[i*256 + dblk*8 + d];
        aadd(curP + b2*256 + dblk*8 + d, s);
      }
    }
    gbar(bar, wg, ++bn);

    // ===== P4: GRU1 via fused M1 + decin side-dot; d1 = h1' + decin =====
    {
      float* yL  = BUF;             // [16][516]: [0:256)=att_h', [256:512)=ctxN
      float* h1L = BUF + 8256;      // [16][260]
      const float* gA = attH + w*16384 + b0*256;
      const float* gH = h1a + rb*16384 + b0*256;
      const float* gC = curP + b0*256;
      f32x4 vA0 = cload16(gA + (r0<<8) + c0), vA1 = cload16(gA + (r1<<8) + c0);
      f32x4 vH0 = cload16(gH + (r0<<8) + c0), vH1 = cload16(gH + (r1<<8) + c0);
      f32x4 vC0 = cload16(gC + (r0<<8) + c0), vC1 = cload16(gC + (r1<<8) + c0);
      float s0 = aload4(attS + b0 + r0), s1 = aload4(attS + b0 + r1);
      asm volatile("s_waitcnt vmcnt(0)" : "+v"(vA0),"+v"(vA1),"+v"(vH0),"+v"(vH1),"+v"(vC0),"+v"(vC1));
      float iv0 = s0 > 0.f ? 1.f/s0 : 0.f, iv1 = s1 > 0.f ? 1.f/s1 : 0.f;
      *(f32x4*)(yL + r0*516 + c0) = vA0;       *(f32x4*)(yL + r1*516 + c0) = vA1;
      *(f32x4*)(h1L + r0*260 + c0) = vH0;      *(f32x4*)(h1L + r1*260 + c0) = vH1;
      *(f32x4*)(yL + r0*516 + 256 + c0) = vC0*iv0; *(f32x4*)(yL + r1*516 + 256 + c0) = vC1*iv1;
      __syncthreads();
      if (x < 12)
        ewGi[cs*16 + bq] = bdot<64>(blob + BO_M1 + cs*512, yL + bq*516) + C1v[col];
      else if (x < 24)
        ewGh[cs*16 + bq] = bdot<32>(blob + BO_H1 + cs*256, h1L + bq*260) + d1Bh[col];
      else {
        int idx = tid - 384;
        int bq2 = idx & 15, cc = (idx >> 4) & 3, half = idx >> 6;
        pdec[idx] = bdot<32>(blob + BO_PJ + cc*512 + half*256, yL + bq2*516 + half*256);
      }
      __syncthreads();
      if (tid < 64){
        int bt = tid & 15, jj = tid >> 4;
        int j = sl*4 + jj;
        float ir = ewGi[(jj*3+0)*16+bt] + ewGh[(jj*3+0)*16+bt];
        float iz = ewGi[(jj*3+1)*16+bt] + ewGh[(jj*3+1)*16+bt];
        float inn = ewGi[(jj*3+2)*16+bt];
        float hn  = ewGh[(jj*3+2)*16+bt];
        float rg = fsig(ir), z = fsig(iz);
        float n = ftanh(inn + rg * hn);
        float hv = h1L[bt*260 + j];
        float hnew = (1.f - z)*n + z*hv;
        float dec = pdec[jj*16 + bt] + pdec[64 + jj*16 + bt] + projB[j];
        astore4(h1a + w*16384 + (b0+bt)*256 + j, hnew);
        astore4(d1v + (b0+bt)*256 + j, hnew + dec);
      }
      if (sl == 0 && tid < 16)
        ws[OFF_SUMS + t*64 + b0 + tid] = aload4(attS + b0 + tid);
    }
    gbar(bar, wg, ++bn);

    // ===== P5: GRU2; d2 = h2' + d1 (feeds outputs only; no barrier) =====
    {
      float* dL  = BUF;             // [16][260]
      float* h2L = BUF + 4160;      // [16][260]
      const float* gD = d1v + b0*256;
      const float* gH = h2a + rb*16384 + b0*256;
      f32x4 vD0 = cload16(gD + (r0<<8) + c0), vD1 = cload16(gD + (r1<<8) + c0);
      f32x4 vH0 = cload16(gH + (r0<<8) + c0), vH1 = cload16(gH + (r1<<8) + c0);
      asm volatile("s_waitcnt vmcnt(0)" : "+v"(vD0),"+v"(vD1),"+v"(vH0),"+v"(vH1));
      *(f32x4*)(dL + r0*260 + c0) = vD0;  *(f32x4*)(dL + r1*260 + c0) = vD1;
      *(f32x4*)(h2L + r0*260 + c0) = vH0; *(f32x4*)(h2L + r1*260 + c0) = vH1;
      __syncthreads();
      if (x < 12)
        ewGi[cs*16 + bq] = bdot<32>(blob + BO_I2 + cs*256, dL + bq*260) + d2Bi[col];
      else if (x < 24)
        ewGh[cs*16 + bq] = bdot<32>(blob + BO_H2 + cs*256, h2L + bq*260) + d2Bh[col];
      __syncthreads();
      if (tid < 64){
        int bt = tid & 15, jj = tid >> 4;
        int j = sl*4 + jj;
        float ir = ewGi[(jj*3+0)*16+bt] + ewGh[(jj*3+0)*16+bt];
        float iz = ewGi[(jj*3+1)*16+bt] + ewGh[(jj*3+1)*16+bt];
        float inn = ewGi[(jj*3+2)*16+bt];
        float hn  = ewGh[(jj*3+2)*16+bt];
        float rg = fsig(ir), z = fsig(iz);
        float n = ftanh(inn + rg * hn);
        float hv = h2L[bt*260 + j];
        float hnew = (1.f - z)*n + z*hv;
        astore4(h2a + w*16384 + (b0+bt)*256 + j, hnew);
        d2a[t*16384 + j*64 + (b0+bt)] = hnew + dL[bt*260 + j];
      }
      __syncthreads();  // protect BUF/ew from next-iteration P0
    }
  }
}

// ---------------- alignment rescale ----------------
__global__ __launch_bounds__(NTH, 1) void rescale_k(const float* __restrict__ ws,
                                                    float* __restrict__ out){
  int blk = blockIdx.x;
  int b = blk / TDEC, t = blk - b * TDEC;
  float s = ws[OFF_SUMS + t*64 + b];
  float inv = (s > 0.f) ? 1.f/s : 0.f;
  out[AOFF + (size_t)blk*512 + threadIdx.x] *= inv;
}

// ---------------- deferred mel/gate heads ----------------
__global__ __launch_bounds__(NTH, 1) void outproj_k(const float* __restrict__ ws,
    float* __restrict__ out, const float* __restrict__ melW, const float* __restrict__ melB,
    const float* __restrict__ gateW, const float* __restrict__ gateB){
  int t = blockIdx.x, tid = threadIdx.x;
  int cx = tid & 255, bh = tid >> 8;
  const float* src = ws + OFF_D2A + t*16384 + bh*32;
  float acc[32];
  #pragma unroll
  for (int i = 0; i < 32; ++i) acc[i] = 0.f;
  bool ismel = (cx < 160);
  bool isgate = (cx >= 160 && cx < 162);
  for (int j = 0; j < 256; ++j){
    float wv = 0.f;
    if (ismel) wv = melW[j*160 + cx];
    else if (isgate) wv = gateW[j*2 + (cx - 160)];
    const f32x4* dp = (const f32x4*)(src + j*64);
    f32x4 vv[8];
    #pragma unroll
    for (int q = 0; q < 8; ++q) vv[q] = dp[q];
    #pragma unroll
    for (int q = 0; q < 8; ++q){
      acc[q*4+0] += vv[q][0]*wv; acc[q*4+1] += vv[q][1]*wv;
      acc[q*4+2] += vv[q][2]*wv; acc[q*4+3] += vv[q][3]*wv;
    }
  }
  if (ismel){
    float bb = melB[cx];
    #pragma unroll
    for (int i = 0; i < 32; ++i){
      int b = bh*32 + i;
      out[((size_t)(b*TDEC + t))*160 + cx] = acc[i] + bb;
    }
  } else if (isgate){
    int g = cx - 160;
    float bb = gateB[g];
    #pragma unroll
    for (int i = 0; i < 32; ++i){
      int b = bh*32 + i;
      out[GOFF + ((size_t)(b*TDEC + t))*2 + g] = fsig(acc[i] + bb);
    }
  }
}

extern "C" void kernel_launch(void* const* d_in, const int* in_sizes, int n_in,
                              void* d_out, int out_size, void* d_ws, size_t ws_size,
                              hipStream_t stream)
{
  (void)in_sizes; (void)n_in; (void)out_size; (void)ws_size;
  const float* enc   = (const float*)d_in[0];
  const float* inp   = (const float*)d_in[1];
  const int*   mlen  = (const int*)d_in[2];
  const float* preW1 = (const float*)d_in[3];
  const float* preB1 = (const float*)d_in[4];
  const float* preW2 = (const float*)d_in[5];
  const float* preB2 = (const float*)d_in[6];
  const float* memW  = (const float*)d_in[7];
  const float* qW    = (const float*)d_in[8];
  const float* vW    = (const float*)d_in[9];
  const float* attWi = (const float*)d_in[10];
  const float* attWh = (const float*)d_in[11];
  const float* attBi = (const float*)d_in[12];
  const float* attBh = (const float*)d_in[13];
  const float* projW = (const float*)d_in[14];
  const float* projB = (const float*)d_in[15];
  const float* d1Wi  = (const float*)d_in[16];
  const float* d1Wh  = (const float*)d_in[17];
  const float* d1Bi  = (const float*)d_in[18];
  const float* d1Bh  = (const float*)d_in[19];
  const float* d2Wi  = (const float*)d_in[20];
  const float* d2Wh  = (const float*)d_in[21];
  const float* d2Bi  = (const float*)d_in[22];
  const float* d2Bh  = (const float*)d_in[23];
  const float* melW  = (const float*)d_in[24];
  const float* melB  = (const float*)d_in[25];
  const float* gateW = (const float*)d_in[26];
  const float* gateB = (const float*)d_in[27];
  float* ws = (float*)d_ws;
  float* out = (float*)d_out;

  hipMemsetAsync(d_ws, 0, (size_t)ZERO_FLOATS * sizeof(float), stream);

  dim3 tt(256);
  transpose_k<<<dim3(24, 12), tt, 0, stream>>>(attWi, ws + T_WIT_A, 384, 768);
  transpose_k<<<dim3(24, 8),  tt, 0, stream>>>(attWh, ws + T_WHT_A, 256, 768);
  transpose_k<<<dim3(24, 8),  tt, 0, stream>>>(d1Wh,  ws + T_WHT1, 256, 768);
  transpose_k<<<dim3(24, 8),  tt, 0, stream>>>(d2Wi,  ws + T_WIT2, 256, 768);
  transpose_k<<<dim3(24, 8),  tt, 0, stream>>>(d2Wh,  ws + T_WHT2, 256, 768);
  transpose_k<<<dim3(8, 16),  tt, 0, stream>>>(projW, ws + T_PJT, 512, 256);
  transpose_k<<<dim3(8, 8),   tt, 0, stream>>>(qW,    ws + T_QWT, 256, 256);
  fuse_k<<<3072, 128, 0, stream>>>(projW, d1Wi, ws + T_M1);
  c1_k<<<3, 256, 0, stream>>>(projB, d1Wi, d1Bi, ws + OFF_C1);
  transpose_k<<<dim3(24, 16), tt, 0, stream>>>(ws + T_M1, ws + T_M1T, 512, 768);
  pack_k<<<64, NTH, 0, stream>>>(ws);

  prenet_k<<<dim3(TDEC, 2), NTH, 0, stream>>>(ws, inp, preW1, preB1, preW2, preB2);
  pm_k<<<512, NTH, 0, stream>>>(ws, enc, memW);
  decoder_k<<<NWG, NTH, 0, stream>>>(ws, out, mlen, vW, attBi, attBh, projB,
                                     d1Bh, d2Bi, d2Bh);
  rescale_k<<<64 * TDEC, NTH, 0, stream>>>(ws, out);
  outproj_k<<<TDEC, NTH, 0, stream>>>(ws, out, melW, melB, gateW, gateB);
}